// Round 1
// baseline (2525.005 us; speedup 1.0000x reference)
//
#include <hip/hip_runtime.h>
#include <math.h>

#define NB   256
#define LSEQ 1800
#define NF   50
#define NE   4
#define NH   32
#define G3   96
#define ND   64
#define NHU  32
#define CHUNK 60
#define TBLK  12
#define NCHUNK (LSEQ / CHUNK)   // 30
#define NBLK   (CHUNK / TBLK)   // 5

// ---------------------------------------------------------------------------
// Kernel 1: fold input projection into layer-0 input weights.
// C[e][f][g] = sum_d Wih0[e][g][d] * W_in[d][f]   (stored f-major for LDS copy)
// ---------------------------------------------------------------------------
__global__ void compute_C_kernel(const float* __restrict__ Wih0,
                                 const float* __restrict__ W_in,
                                 float* __restrict__ Cg) {
    int e = blockIdx.x;
    for (int idx = threadIdx.x; idx < NF * G3; idx += blockDim.x) {
        int f = idx / G3;
        int g = idx - f * G3;
        const float* wr = Wih0 + ((size_t)e * G3 + g) * ND;
        float s = 0.f;
        #pragma unroll 8
        for (int d = 0; d < ND; d++) s += wr[d] * W_in[d * NF + f];
        Cg[(size_t)e * NF * G3 + idx] = s;
    }
}

__device__ __forceinline__ float sigmoidf_(float v) {
    return 1.f / (1.f + expf(-v));
}

// ---------------------------------------------------------------------------
// Main kernel: one 64-thread block per (batch, expert). Unrouted blocks exit.
// Thread (j = tid&31, hlf = tid>>5) owns gate rows {j, j+32, j+64}, k-half
// [16*hlf, 16*hlf+16). Half-dots combined with shfl_xor(32). Single wave =>
// cheap barriers, wave-synchronous LDS.
// ---------------------------------------------------------------------------
__global__ __launch_bounds__(64, 1)
void moe_gru_kernel(const float* __restrict__ x,
                    const int*   __restrict__ horizon,
                    const float* __restrict__ emb,
                    const float* __restrict__ W_gate,
                    const float* __restrict__ b_gate,
                    const float* __restrict__ b_in,
                    const float* __restrict__ Wih0,
                    const float* __restrict__ Whh0,
                    const float* __restrict__ bih0,
                    const float* __restrict__ bhh0,
                    const float* __restrict__ Wih1,
                    const float* __restrict__ Whh1,
                    const float* __restrict__ bih1,
                    const float* __restrict__ bhh1,
                    const float* __restrict__ Wh1,
                    const float* __restrict__ bh1,
                    const float* __restrict__ Wh2,
                    const float* __restrict__ bh2,
                    const float* __restrict__ Cg,
                    float* __restrict__ out) {
    __shared__ __align__(16) float smem[4800 + 3008 + 64 + 64 + 32 + 32];
    float* CT  = smem;                  // [f][96]  folded input weights
    float* xs  = smem + 4800;           // [f][CHUNK] transposed x chunk
    float* heL = smem + 4800 + 3008;    // 64: h_embed
    float* bbL = heL + 64;              // 64: b_in + h_embed
    float* h0L = bbL + 64;              // 32
    float* h1L = h0L + 32;              // 32

    const int bid = blockIdx.x;
    const int b   = bid >> 2;
    const int e   = bid & 3;
    const int tid = threadIdx.x;
    const int j   = tid & 31;
    const int hlf = tid >> 5;
    const int k0  = hlf << 4;

    // ---- stage h_embed / (b_in + h_embed) ----
    {
        int hor = horizon[b];
        float he = emb[(size_t)hor * ND + tid];
        heL[tid] = he;
        bbL[tid] = he + b_in[tid];
    }
    __syncthreads();

    // ---- gating (every thread computes identically) ----
    float lg[NE];
    #pragma unroll
    for (int q = 0; q < NE; q++) {
        float s = b_gate[q];
        for (int d = 0; d < ND; d++) s += heL[d] * W_gate[q * ND + d];
        lg[q] = s;
    }
    int i1 = 0;
    #pragma unroll
    for (int q = 1; q < NE; q++) if (lg[q] > lg[i1]) i1 = q;
    int i2 = (i1 == 0) ? 1 : 0;
    #pragma unroll
    for (int q = 0; q < NE; q++) if (q != i1 && lg[q] > lg[i2]) i2 = q;
    if (e != i1 && e != i2) return;          // block-uniform
    const float ex2 = expf(lg[i2] - lg[i1]);
    const float wgt = (e == i1) ? (1.f / (1.f + ex2)) : (ex2 / (1.f + ex2));

    // ---- stage folded input weights for this expert ----
    for (int idx = tid; idx < NF * G3; idx += 64)
        CT[idx] = Cg[(size_t)e * NF * G3 + idx];

    // ---- per-thread register weights: rows {j, j+32, j+64}, k in [k0,k0+16) ----
    float wh0[3][16], wi1[3][16], wh1[3][16];
    float bhh0r[3], bih1r[3], bhh1r[3], dreg[3];
    #pragma unroll
    for (int c = 0; c < 3; c++) {
        const int row = j + 32 * c;
        {
            const float4* p = (const float4*)(Whh0 + ((size_t)e * G3 + row) * NH + k0);
            float4 A0 = p[0], A1 = p[1], A2 = p[2], A3 = p[3];
            wh0[c][0]=A0.x; wh0[c][1]=A0.y; wh0[c][2]=A0.z; wh0[c][3]=A0.w;
            wh0[c][4]=A1.x; wh0[c][5]=A1.y; wh0[c][6]=A1.z; wh0[c][7]=A1.w;
            wh0[c][8]=A2.x; wh0[c][9]=A2.y; wh0[c][10]=A2.z; wh0[c][11]=A2.w;
            wh0[c][12]=A3.x; wh0[c][13]=A3.y; wh0[c][14]=A3.z; wh0[c][15]=A3.w;
        }
        {
            const float4* p = (const float4*)(Wih1 + ((size_t)e * G3 + row) * NH + k0);
            float4 A0 = p[0], A1 = p[1], A2 = p[2], A3 = p[3];
            wi1[c][0]=A0.x; wi1[c][1]=A0.y; wi1[c][2]=A0.z; wi1[c][3]=A0.w;
            wi1[c][4]=A1.x; wi1[c][5]=A1.y; wi1[c][6]=A1.z; wi1[c][7]=A1.w;
            wi1[c][8]=A2.x; wi1[c][9]=A2.y; wi1[c][10]=A2.z; wi1[c][11]=A2.w;
            wi1[c][12]=A3.x; wi1[c][13]=A3.y; wi1[c][14]=A3.z; wi1[c][15]=A3.w;
        }
        {
            const float4* p = (const float4*)(Whh1 + ((size_t)e * G3 + row) * NH + k0);
            float4 A0 = p[0], A1 = p[1], A2 = p[2], A3 = p[3];
            wh1[c][0]=A0.x; wh1[c][1]=A0.y; wh1[c][2]=A0.z; wh1[c][3]=A0.w;
            wh1[c][4]=A1.x; wh1[c][5]=A1.y; wh1[c][6]=A1.z; wh1[c][7]=A1.w;
            wh1[c][8]=A2.x; wh1[c][9]=A2.y; wh1[c][10]=A2.z; wh1[c][11]=A2.w;
            wh1[c][12]=A3.x; wh1[c][13]=A3.y; wh1[c][14]=A3.z; wh1[c][15]=A3.w;
        }
        bhh0r[c] = bhh0[e * G3 + row];
        bih1r[c] = bih1[e * G3 + row];
        bhh1r[c] = bhh1[e * G3 + row];
        // dvec = bih0 + Wih0 @ (b_in + h_embed); added only by half 0
        float s = bih0[e * G3 + row];
        const float* wr = Wih0 + ((size_t)e * G3 + row) * ND;
        for (int d = 0; d < ND; d++) s += wr[d] * bbL[d];
        dreg[c] = hlf ? 0.f : s;
    }

    float h0r[16], h1r[16];
    #pragma unroll
    for (int k = 0; k < 16; k++) { h0r[k] = 0.f; h1r[k] = 0.f; }
    if (tid < 32) { h0L[tid] = 0.f; h1L[tid] = 0.f; }
    __syncthreads();

    const float* xg = x + (size_t)b * LSEQ * NF;

    for (int ch = 0; ch < NCHUNK; ch++) {
        // stage x chunk, transposed to [f][t] for vectorized time reads
        {
            const float* xc = xg + (size_t)ch * CHUNK * NF;
            for (int idx = tid; idx < CHUNK * NF; idx += 64) {
                float v = xc[idx];
                int it = idx / NF;
                int f  = idx - it * NF;
                xs[f * CHUNK + it] = v;
            }
        }
        __syncthreads();

        for (int blk = 0; blk < NBLK; blk++) {
            const int ib0 = blk * TBLK;
            // ---- xg0 partial (this half's 25 features) for TBLK steps ----
            float acc0[TBLK], acc1[TBLK], acc2[TBLK];
            #pragma unroll
            for (int i = 0; i < TBLK; i++) {
                acc0[i] = dreg[0]; acc1[i] = dreg[1]; acc2[i] = dreg[2];
            }
            #pragma unroll 5
            for (int f = 0; f < 25; f++) {
                const int fg = f + 25 * hlf;
                float c0 = CT[fg * G3 + j];
                float c1 = CT[fg * G3 + j + 32];
                float c2 = CT[fg * G3 + j + 64];
                const float4* xp = (const float4*)(xs + fg * CHUNK + ib0);
                float4 xa = xp[0], xb = xp[1], xc4 = xp[2];
                float xv[TBLK] = {xa.x, xa.y, xa.z, xa.w,
                                  xb.x, xb.y, xb.z, xb.w,
                                  xc4.x, xc4.y, xc4.z, xc4.w};
                #pragma unroll
                for (int i = 0; i < TBLK; i++) {
                    acc0[i] += c0 * xv[i];
                    acc1[i] += c1 * xv[i];
                    acc2[i] += c2 * xv[i];
                }
            }

            // ---- TBLK recurrence steps ----
            #pragma unroll
            for (int i = 0; i < TBLK; i++) {
                // layer 0: gh0 half-dots
                float p0 = hlf ? 0.f : bhh0r[0];
                float p1 = hlf ? 0.f : bhh0r[1];
                float p2 = hlf ? 0.f : bhh0r[2];
                #pragma unroll
                for (int k = 0; k < 16; k++) {
                    p0 += wh0[0][k] * h0r[k];
                    p1 += wh0[1][k] * h0r[k];
                    p2 += wh0[2][k] * h0r[k];
                }
                float sr = acc0[i] + p0;
                float sz = acc1[i] + p1;
                float xn = acc2[i];
                sr += __shfl_xor(sr, 32, 64);
                sz += __shfl_xor(sz, 32, 64);
                xn += __shfl_xor(xn, 32, 64);
                float gn = p2 + __shfl_xor(p2, 32, 64);
                float r = sigmoidf_(sr);
                float z = sigmoidf_(sz);
                float n = tanhf(xn + r * gn);
                float hold = h0L[j];
                float hnew = n + z * (hold - n);
                if (!hlf) h0L[j] = hnew;
                __syncthreads();
                {
                    const float4* hp = (const float4*)(h0L + k0);
                    float4 a0 = hp[0], a1 = hp[1], a2 = hp[2], a3 = hp[3];
                    h0r[0]=a0.x;  h0r[1]=a0.y;  h0r[2]=a0.z;  h0r[3]=a0.w;
                    h0r[4]=a1.x;  h0r[5]=a1.y;  h0r[6]=a1.z;  h0r[7]=a1.w;
                    h0r[8]=a2.x;  h0r[9]=a2.y;  h0r[10]=a2.z; h0r[11]=a2.w;
                    h0r[12]=a3.x; h0r[13]=a3.y; h0r[14]=a3.z; h0r[15]=a3.w;
                }
                // layer 1: xg1 (from new h0) and gh1 (from h1) half-dots
                float q0 = hlf ? 0.f : bih1r[0];
                float q1 = hlf ? 0.f : bih1r[1];
                float q2 = hlf ? 0.f : bih1r[2];
                float g0 = hlf ? 0.f : bhh1r[0];
                float g1 = hlf ? 0.f : bhh1r[1];
                float g2 = hlf ? 0.f : bhh1r[2];
                #pragma unroll
                for (int k = 0; k < 16; k++) {
                    q0 += wi1[0][k] * h0r[k];
                    q1 += wi1[1][k] * h0r[k];
                    q2 += wi1[2][k] * h0r[k];
                    g0 += wh1[0][k] * h1r[k];
                    g1 += wh1[1][k] * h1r[k];
                    g2 += wh1[2][k] * h1r[k];
                }
                float s1r = q0 + g0;
                float s1z = q1 + g1;
                s1r += __shfl_xor(s1r, 32, 64);
                s1z += __shfl_xor(s1z, 32, 64);
                float xn1 = q2 + __shfl_xor(q2, 32, 64);
                float gn1 = g2 + __shfl_xor(g2, 32, 64);
                float r1 = sigmoidf_(s1r);
                float z1 = sigmoidf_(s1z);
                float n1 = tanhf(xn1 + r1 * gn1);
                float h1old = h1L[j];
                float h1new = n1 + z1 * (h1old - n1);
                if (!hlf) h1L[j] = h1new;
                __syncthreads();
                {
                    const float4* hp = (const float4*)(h1L + k0);
                    float4 a0 = hp[0], a1 = hp[1], a2 = hp[2], a3 = hp[3];
                    h1r[0]=a0.x;  h1r[1]=a0.y;  h1r[2]=a0.z;  h1r[3]=a0.w;
                    h1r[4]=a1.x;  h1r[5]=a1.y;  h1r[6]=a1.z;  h1r[7]=a1.w;
                    h1r[8]=a2.x;  h1r[9]=a2.y;  h1r[10]=a2.z; h1r[11]=a2.w;
                    h1r[12]=a3.x; h1r[13]=a3.y; h1r[14]=a3.z; h1r[15]=a3.w;
                }
            }
        }
        __syncthreads();
    }

    // ---- head MLP + weighted accumulation ----
    if (tid < 32) {
        float s = bh1[e * NHU + tid];
        const float* wr = Wh1 + ((size_t)e * NHU + tid) * NH;
        #pragma unroll
        for (int d = 0; d < NH; d++) s += wr[d] * h1L[d];
        float hid = fmaxf(s, 0.f);
        float c = hid * Wh2[e * NHU + tid];
        #pragma unroll
        for (int off = 16; off > 0; off >>= 1) c += __shfl_down(c, off, 64);
        if (tid == 0) atomicAdd(out + b, wgt * (c + bh2[e]));
    }
}

extern "C" void kernel_launch(void* const* d_in, const int* in_sizes, int n_in,
                              void* d_out, int out_size, void* d_ws, size_t ws_size,
                              hipStream_t stream) {
    const float* x       = (const float*)d_in[0];
    const int*   horizon = (const int*)  d_in[1];
    const float* W_in    = (const float*)d_in[2];
    const float* b_in    = (const float*)d_in[3];
    const float* emb     = (const float*)d_in[4];
    const float* W_gate  = (const float*)d_in[5];
    const float* b_gate  = (const float*)d_in[6];
    const float* Wih0    = (const float*)d_in[7];
    const float* Whh0    = (const float*)d_in[8];
    const float* bih0    = (const float*)d_in[9];
    const float* bhh0    = (const float*)d_in[10];
    const float* Wih1    = (const float*)d_in[11];
    const float* Whh1    = (const float*)d_in[12];
    const float* bih1    = (const float*)d_in[13];
    const float* bhh1    = (const float*)d_in[14];
    const float* Wh1     = (const float*)d_in[15];
    const float* bh1     = (const float*)d_in[16];
    const float* Wh2     = (const float*)d_in[17];
    const float* bh2     = (const float*)d_in[18];
    float* out = (float*)d_out;
    float* Cg  = (float*)d_ws;   // NE*NF*G3 floats = 76.8 KB

    hipMemsetAsync(d_out, 0, NB * sizeof(float), stream);
    compute_C_kernel<<<dim3(NE), dim3(256), 0, stream>>>(Wih0, W_in, Cg);
    moe_gru_kernel<<<dim3(NB * NE), dim3(64), 0, stream>>>(
        x, horizon, emb, W_gate, b_gate, b_in,
        Wih0, Whh0, bih0, bhh0, Wih1, Whh1, bih1, bhh1,
        Wh1, bh1, Wh2, bh2, Cg, out);
}

// Round 2
// 1685.842 us; speedup vs baseline: 1.4978x; 1.4978x over previous
//
#include <hip/hip_runtime.h>
#include <math.h>

#define NB   256
#define LSEQ 1800
#define NF   50
#define NE   4
#define NH   32
#define G3   96
#define ND   64
#define NHU  32
#define CHUNK 60
#define TBLK  12
#define NCHUNK (LSEQ / CHUNK)   // 30
#define NBLK   (CHUNK / TBLK)   // 5

// ---------------------------------------------------------------------------
// Kernel 1: fold input projection into layer-0 input weights.
// C[e][f][g] = sum_d Wih0[e][g][d] * W_in[d][f]   (stored f-major for LDS copy)
// ---------------------------------------------------------------------------
__global__ void compute_C_kernel(const float* __restrict__ Wih0,
                                 const float* __restrict__ W_in,
                                 float* __restrict__ Cg) {
    int e = blockIdx.x;
    for (int idx = threadIdx.x; idx < NF * G3; idx += blockDim.x) {
        int f = idx / G3;
        int g = idx - f * G3;
        const float* wr = Wih0 + ((size_t)e * G3 + g) * ND;
        float s = 0.f;
        #pragma unroll 8
        for (int d = 0; d < ND; d++) s += wr[d] * W_in[d * NF + f];
        Cg[(size_t)e * NF * G3 + idx] = s;
    }
}

// Fast transcendentals: v_exp_f32 computes 2^x; v_rcp_f32 is ~1 ulp.
// sigmoid: large +x -> exp2 -> 0 -> 1; large -x -> exp2 -> inf -> rcp(inf)=0. Safe.
__device__ __forceinline__ float fsig(float x) {
    float e = __builtin_amdgcn_exp2f(-1.442695041f * x);
    return __builtin_amdgcn_rcpf(1.f + e);
}
// tanh = (1-e)/(1+e), e = exp2(-2x*log2e). Clamp low side to avoid inf*0=NaN.
__device__ __forceinline__ float ftanh(float x) {
    x = fmaxf(x, -20.f);
    float e = __builtin_amdgcn_exp2f(-2.885390082f * x);
    return (1.f - e) * __builtin_amdgcn_rcpf(1.f + e);
}

// ---------------------------------------------------------------------------
// Main kernel: one 64-thread (single-wave) block per (batch, expert).
// Unrouted blocks exit. Thread (j = tid&31, hlf = tid>>5) owns gate rows
// {j, j+32, j+64}, k-half [16*hlf, 16*hlf+16). Half-dots combined with
// shfl_xor(32). Single wave => NO barriers anywhere: LDS is wave-synchronous
// (lockstep 64-lane wave, DS ops complete in program order). This lets the
// compiler software-pipeline across the h-exchanges.
// ---------------------------------------------------------------------------
__global__ __launch_bounds__(64, 1)
void moe_gru_kernel(const float* __restrict__ x,
                    const int*   __restrict__ horizon,
                    const float* __restrict__ emb,
                    const float* __restrict__ W_gate,
                    const float* __restrict__ b_gate,
                    const float* __restrict__ b_in,
                    const float* __restrict__ Wih0,
                    const float* __restrict__ Whh0,
                    const float* __restrict__ bih0,
                    const float* __restrict__ bhh0,
                    const float* __restrict__ Wih1,
                    const float* __restrict__ Whh1,
                    const float* __restrict__ bih1,
                    const float* __restrict__ bhh1,
                    const float* __restrict__ Wh1,
                    const float* __restrict__ bh1,
                    const float* __restrict__ Wh2,
                    const float* __restrict__ bh2,
                    const float* __restrict__ Cg,
                    float* __restrict__ out) {
    __shared__ __align__(16) float smem[4800 + 3008 + 64 + 64 + 32 + 32];
    float* CT  = smem;                  // [f][96]  folded input weights
    float* xs  = smem + 4800;           // [f][CHUNK] transposed x chunk
    float* heL = smem + 4800 + 3008;    // 64: h_embed
    float* bbL = heL + 64;              // 64: b_in + h_embed
    float* h0L = bbL + 64;              // 32
    float* h1L = h0L + 32;              // 32

    const int bid = blockIdx.x;
    const int b   = bid >> 2;
    const int e   = bid & 3;
    const int tid = threadIdx.x;
    const int j   = tid & 31;
    const int hlf = tid >> 5;
    const int k0  = hlf << 4;

    // ---- stage h_embed / (b_in + h_embed) (wave-synchronous, no barrier) ----
    {
        int hor = horizon[b];
        float he = emb[(size_t)hor * ND + tid];
        heL[tid] = he;
        bbL[tid] = he + b_in[tid];
    }

    // ---- gating (every thread computes identically) ----
    float lg[NE];
    #pragma unroll
    for (int q = 0; q < NE; q++) {
        float s = b_gate[q];
        for (int d = 0; d < ND; d++) s += heL[d] * W_gate[q * ND + d];
        lg[q] = s;
    }
    int i1 = 0;
    #pragma unroll
    for (int q = 1; q < NE; q++) if (lg[q] > lg[i1]) i1 = q;
    int i2 = (i1 == 0) ? 1 : 0;
    #pragma unroll
    for (int q = 0; q < NE; q++) if (q != i1 && lg[q] > lg[i2]) i2 = q;
    if (e != i1 && e != i2) return;          // block-uniform
    const float ex2 = expf(lg[i2] - lg[i1]);
    const float wgt = (e == i1) ? (1.f / (1.f + ex2)) : (ex2 / (1.f + ex2));

    // ---- stage folded input weights for this expert ----
    for (int idx = tid; idx < NF * G3; idx += 64)
        CT[idx] = Cg[(size_t)e * NF * G3 + idx];

    // ---- per-thread register weights: rows {j, j+32, j+64}, k in [k0,k0+16) ----
    float wh0[3][16], wi1[3][16], wh1[3][16];
    float bhh0r[3], bih1r[3], bhh1r[3], dreg[3];
    #pragma unroll
    for (int c = 0; c < 3; c++) {
        const int row = j + 32 * c;
        {
            const float4* p = (const float4*)(Whh0 + ((size_t)e * G3 + row) * NH + k0);
            float4 A0 = p[0], A1 = p[1], A2 = p[2], A3 = p[3];
            wh0[c][0]=A0.x; wh0[c][1]=A0.y; wh0[c][2]=A0.z; wh0[c][3]=A0.w;
            wh0[c][4]=A1.x; wh0[c][5]=A1.y; wh0[c][6]=A1.z; wh0[c][7]=A1.w;
            wh0[c][8]=A2.x; wh0[c][9]=A2.y; wh0[c][10]=A2.z; wh0[c][11]=A2.w;
            wh0[c][12]=A3.x; wh0[c][13]=A3.y; wh0[c][14]=A3.z; wh0[c][15]=A3.w;
        }
        {
            const float4* p = (const float4*)(Wih1 + ((size_t)e * G3 + row) * NH + k0);
            float4 A0 = p[0], A1 = p[1], A2 = p[2], A3 = p[3];
            wi1[c][0]=A0.x; wi1[c][1]=A0.y; wi1[c][2]=A0.z; wi1[c][3]=A0.w;
            wi1[c][4]=A1.x; wi1[c][5]=A1.y; wi1[c][6]=A1.z; wi1[c][7]=A1.w;
            wi1[c][8]=A2.x; wi1[c][9]=A2.y; wi1[c][10]=A2.z; wi1[c][11]=A2.w;
            wi1[c][12]=A3.x; wi1[c][13]=A3.y; wi1[c][14]=A3.z; wi1[c][15]=A3.w;
        }
        {
            const float4* p = (const float4*)(Whh1 + ((size_t)e * G3 + row) * NH + k0);
            float4 A0 = p[0], A1 = p[1], A2 = p[2], A3 = p[3];
            wh1[c][0]=A0.x; wh1[c][1]=A0.y; wh1[c][2]=A0.z; wh1[c][3]=A0.w;
            wh1[c][4]=A1.x; wh1[c][5]=A1.y; wh1[c][6]=A1.z; wh1[c][7]=A1.w;
            wh1[c][8]=A2.x; wh1[c][9]=A2.y; wh1[c][10]=A2.z; wh1[c][11]=A2.w;
            wh1[c][12]=A3.x; wh1[c][13]=A3.y; wh1[c][14]=A3.z; wh1[c][15]=A3.w;
        }
        bhh0r[c] = bhh0[e * G3 + row];
        bih1r[c] = bih1[e * G3 + row];
        bhh1r[c] = bhh1[e * G3 + row];
        // dvec = bih0 + Wih0 @ (b_in + h_embed); added only by half 0
        float s = bih0[e * G3 + row];
        const float* wr = Wih0 + ((size_t)e * G3 + row) * ND;
        for (int d = 0; d < ND; d++) s += wr[d] * bbL[d];
        dreg[c] = hlf ? 0.f : s;
    }

    float h0r[16], h1r[16];
    #pragma unroll
    for (int k = 0; k < 16; k++) { h0r[k] = 0.f; h1r[k] = 0.f; }
    // h_old carried in registers: both halves compute identical h_new each step.
    float h0old = 0.f, h1old = 0.f;
    if (tid < 32) { h0L[tid] = 0.f; h1L[tid] = 0.f; }

    const float* xg = x + (size_t)b * LSEQ * NF;

    for (int ch = 0; ch < NCHUNK; ch++) {
        // stage x chunk (contiguous float4 global loads), transpose to [f][t]
        {
            const float4* xc4 = (const float4*)(xg + (size_t)ch * CHUNK * NF);
            for (int i4 = tid; i4 < (CHUNK * NF) / 4; i4 += 64) {
                float4 v = xc4[i4];
                int idx = i4 * 4;
                #pragma unroll
                for (int u = 0; u < 4; u++) {
                    int id = idx + u;
                    int it = (int)(((unsigned)id * 5243u) >> 18);   // id/50
                    int f  = id - it * 50;
                    float val = (u == 0) ? v.x : (u == 1) ? v.y : (u == 2) ? v.z : v.w;
                    xs[f * CHUNK + it] = val;
                }
            }
        }
        // no barrier: single wave, DS ops in program order

        for (int blk = 0; blk < NBLK; blk++) {
            const int ib0 = blk * TBLK;
            // ---- xg0 partial (this half's 25 features) for TBLK steps ----
            float acc0[TBLK], acc1[TBLK], acc2[TBLK];
            #pragma unroll
            for (int i = 0; i < TBLK; i++) {
                acc0[i] = dreg[0]; acc1[i] = dreg[1]; acc2[i] = dreg[2];
            }
            #pragma unroll 5
            for (int f = 0; f < 25; f++) {
                const int fg = f + 25 * hlf;
                float c0 = CT[fg * G3 + j];
                float c1 = CT[fg * G3 + j + 32];
                float c2 = CT[fg * G3 + j + 64];
                const float4* xp = (const float4*)(xs + fg * CHUNK + ib0);
                float4 xa = xp[0], xb = xp[1], xc4 = xp[2];
                float xv[TBLK] = {xa.x, xa.y, xa.z, xa.w,
                                  xb.x, xb.y, xb.z, xb.w,
                                  xc4.x, xc4.y, xc4.z, xc4.w};
                #pragma unroll
                for (int i = 0; i < TBLK; i++) {
                    acc0[i] += c0 * xv[i];
                    acc1[i] += c1 * xv[i];
                    acc2[i] += c2 * xv[i];
                }
            }

            // ---- TBLK recurrence steps ----
            #pragma unroll
            for (int i = 0; i < TBLK; i++) {
                // layer 0: gh0 half-dots
                float p0 = hlf ? 0.f : bhh0r[0];
                float p1 = hlf ? 0.f : bhh0r[1];
                float p2 = hlf ? 0.f : bhh0r[2];
                #pragma unroll
                for (int k = 0; k < 16; k++) {
                    p0 += wh0[0][k] * h0r[k];
                    p1 += wh0[1][k] * h0r[k];
                    p2 += wh0[2][k] * h0r[k];
                }
                float sr = acc0[i] + p0;
                float sz = acc1[i] + p1;
                float xn = acc2[i];
                sr += __shfl_xor(sr, 32, 64);
                sz += __shfl_xor(sz, 32, 64);
                xn += __shfl_xor(xn, 32, 64);
                float gn = p2 + __shfl_xor(p2, 32, 64);
                float r = fsig(sr);
                float z = fsig(sz);
                float n = ftanh(xn + r * gn);
                float hnew = n + z * (h0old - n);
                h0old = hnew;
                if (!hlf) h0L[j] = hnew;

                // gh1 dots on h1r: independent of the h0 exchange -> covers
                // the DS write->read round trip.
                float g0 = hlf ? 0.f : bhh1r[0];
                float g1 = hlf ? 0.f : bhh1r[1];
                float g2 = hlf ? 0.f : bhh1r[2];
                #pragma unroll
                for (int k = 0; k < 16; k++) {
                    g0 += wh1[0][k] * h1r[k];
                    g1 += wh1[1][k] * h1r[k];
                    g2 += wh1[2][k] * h1r[k];
                }

                // redistribute h0
                {
                    const float4* hp = (const float4*)(h0L + k0);
                    float4 a0 = hp[0], a1 = hp[1], a2 = hp[2], a3 = hp[3];
                    h0r[0]=a0.x;  h0r[1]=a0.y;  h0r[2]=a0.z;  h0r[3]=a0.w;
                    h0r[4]=a1.x;  h0r[5]=a1.y;  h0r[6]=a1.z;  h0r[7]=a1.w;
                    h0r[8]=a2.x;  h0r[9]=a2.y;  h0r[10]=a2.z; h0r[11]=a2.w;
                    h0r[12]=a3.x; h0r[13]=a3.y; h0r[14]=a3.z; h0r[15]=a3.w;
                }

                // layer 1: xg1 dots on new h0
                float q0 = hlf ? 0.f : bih1r[0];
                float q1 = hlf ? 0.f : bih1r[1];
                float q2 = hlf ? 0.f : bih1r[2];
                #pragma unroll
                for (int k = 0; k < 16; k++) {
                    q0 += wi1[0][k] * h0r[k];
                    q1 += wi1[1][k] * h0r[k];
                    q2 += wi1[2][k] * h0r[k];
                }
                float s1r = q0 + g0;
                float s1z = q1 + g1;
                s1r += __shfl_xor(s1r, 32, 64);
                s1z += __shfl_xor(s1z, 32, 64);
                float xn1 = q2 + __shfl_xor(q2, 32, 64);
                float gn1 = g2 + __shfl_xor(g2, 32, 64);
                float r1 = fsig(s1r);
                float z1 = fsig(s1z);
                float n1 = ftanh(xn1 + r1 * gn1);
                float h1new = n1 + z1 * (h1old - n1);
                h1old = h1new;
                if (!hlf) h1L[j] = h1new;
                {
                    const float4* hp = (const float4*)(h1L + k0);
                    float4 a0 = hp[0], a1 = hp[1], a2 = hp[2], a3 = hp[3];
                    h1r[0]=a0.x;  h1r[1]=a0.y;  h1r[2]=a0.z;  h1r[3]=a0.w;
                    h1r[4]=a1.x;  h1r[5]=a1.y;  h1r[6]=a1.z;  h1r[7]=a1.w;
                    h1r[8]=a2.x;  h1r[9]=a2.y;  h1r[10]=a2.z; h1r[11]=a2.w;
                    h1r[12]=a3.x; h1r[13]=a3.y; h1r[14]=a3.z; h1r[15]=a3.w;
                }
            }
        }
    }

    // ---- head MLP + weighted accumulation ----
    if (tid < 32) {
        float s = bh1[e * NHU + tid];
        const float* wr = Wh1 + ((size_t)e * NHU + tid) * NH;
        #pragma unroll
        for (int d = 0; d < NH; d++) s += wr[d] * h1L[d];
        float hid = fmaxf(s, 0.f);
        float c = hid * Wh2[e * NHU + tid];
        #pragma unroll
        for (int off = 16; off > 0; off >>= 1) c += __shfl_down(c, off, 64);
        if (tid == 0) atomicAdd(out + b, wgt * (c + bh2[e]));
    }
}

extern "C" void kernel_launch(void* const* d_in, const int* in_sizes, int n_in,
                              void* d_out, int out_size, void* d_ws, size_t ws_size,
                              hipStream_t stream) {
    const float* x       = (const float*)d_in[0];
    const int*   horizon = (const int*)  d_in[1];
    const float* W_in    = (const float*)d_in[2];
    const float* b_in    = (const float*)d_in[3];
    const float* emb     = (const float*)d_in[4];
    const float* W_gate  = (const float*)d_in[5];
    const float* b_gate  = (const float*)d_in[6];
    const float* Wih0    = (const float*)d_in[7];
    const float* Whh0    = (const float*)d_in[8];
    const float* bih0    = (const float*)d_in[9];
    const float* bhh0    = (const float*)d_in[10];
    const float* Wih1    = (const float*)d_in[11];
    const float* Whh1    = (const float*)d_in[12];
    const float* bih1    = (const float*)d_in[13];
    const float* bhh1    = (const float*)d_in[14];
    const float* Wh1     = (const float*)d_in[15];
    const float* bh1     = (const float*)d_in[16];
    const float* Wh2     = (const float*)d_in[17];
    const float* bh2     = (const float*)d_in[18];
    float* out = (float*)d_out;
    float* Cg  = (float*)d_ws;   // NE*NF*G3 floats = 76.8 KB

    hipMemsetAsync(d_out, 0, NB * sizeof(float), stream);
    compute_C_kernel<<<dim3(NE), dim3(256), 0, stream>>>(Wih0, W_in, Cg);
    moe_gru_kernel<<<dim3(NB * NE), dim3(64), 0, stream>>>(
        x, horizon, emb, W_gate, b_gate, b_in,
        Wih0, Whh0, bih0, bhh0, Wih1, Whh1, bih1, bhh1,
        Wh1, bh1, Wh2, bh2, Cg, out);
}